// Round 4
// baseline (113.430 us; speedup 1.0000x reference)
//
#include <hip/hip_runtime.h>
#include <math.h>

#define NPOS 512
#define DIM  512
#define NB   1024
#define EPSV 1e-5f
#define COS_EPS 1e-8f

// ws float offsets (~1.06 MB total -> L2-resident)
#define OFF_COS   0                          // [512*512] cos(pos_n, pos_m), plain stores
#define OFF_DENOP (NPOS * NPOS)              // [16*512]  deno partials per (neg m-tile, n)
#define OFF_BCEP  (OFF_DENOP + 16 * NPOS)    // [512]     per-block bce partials

__device__ __forceinline__ float softplus_f(float x) {
    return fmaxf(x, 0.f) + __logf(1.f + __expf(-fabsf(x)));
}

__device__ __forceinline__ float dot4(float4 a, float4 b) {
    return a.x * b.x + a.y * b.y + a.z * b.z + a.w * b.w;
}

// ---------------- Kernel 1: everything except closs combine ----------------
// 32n x 32m tile, full k=512, grid (32,16) = 512 blocks = 2 blocks/CU.
// Double-buffered LDS, 2x2 micro-tile. Norms/t1/t2 computed inline from the
// staging registers (no prep kernel, no ws round-trip). Epilogue: BCE ->
// per-block partial (plain store); neg: exp(cos) row-sums -> per-(mtile,n)
// partials (plain store); pos: raw cos -> 1MB buffer.
__global__ __launch_bounds__(256) void mega_kernel(
    const float* __restrict__ pos, const float* __restrict__ neg,
    const float* __restrict__ w, const float* __restrict__ lb,
    float* __restrict__ ws, float* __restrict__ out)
{
    __shared__ __align__(16) float As[2][32][36];
    __shared__ __align__(16) float Bs[2][32][36];
    __shared__ float smInvA[32], smT1A[32], smInvB[32], smT2B[32];
    __shared__ float red[4];

    const int tid = threadIdx.x;
    const int n0 = blockIdx.y * 32;
    const int m0 = blockIdx.x * 32;
    const int bid = blockIdx.y * 32 + blockIdx.x;
    const bool isneg = (m0 >= NPOS);
    const float* Asrc = pos + (size_t)n0 * DIM;
    const float* Bsrc = isneg ? (neg + (size_t)(m0 - NPOS) * DIM)
                              : (pos + (size_t)m0 * DIM);
    const float* w3 = w + 2 * DIM;

    if (bid == 0 && tid == 0) out[0] = 0.f;   // finish is a later dispatch

    const int lr = tid >> 3;       // 0..31 staging row
    const int lc = (tid & 7) << 2; // 0..28 staging col
    const int ti = tid >> 4;       // 0..15
    const int tj = tid & 15;       // 0..15

    float c[2][2] = {{0.f}}, t[2][2] = {{0.f}};
    float ssa = 0.f, ssb = 0.f, t1a = 0.f, t2b = 0.f;

    // prologue staging (chunk 0) + inline norm/t1/t2 accumulation
    float4 a0 = *(const float4*)(Asrc + lr * DIM + lc);
    float4 b0 = *(const float4*)(Bsrc + lr * DIM + lc);
    float4 w1c = *(const float4*)(w + lc);
    float4 w2c = *(const float4*)(w + DIM + lc);
    ssa += dot4(a0, a0);  t1a += dot4(a0, w1c);
    ssb += dot4(b0, b0);  t2b += dot4(b0, w2c);
    *(float4*)&As[0][lr][lc] = a0;
    *(float4*)&Bs[0][lr][lc] = b0;
    __syncthreads();

    #pragma unroll 1
    for (int iter = 0; iter < DIM / 32; ++iter) {
        const int cur = iter & 1;
        const bool more = (iter < DIM / 32 - 1);
        if (more) {   // issue next-chunk loads early (hides L2 latency)
            const float* ap = Asrc + (iter + 1) * 32;
            const float* bp = Bsrc + (iter + 1) * 32;
            a0  = *(const float4*)(ap + lr * DIM + lc);
            b0  = *(const float4*)(bp + lr * DIM + lc);
            w1c = *(const float4*)(w + (iter + 1) * 32 + lc);
            w2c = *(const float4*)(w + DIM + (iter + 1) * 32 + lc);
        }
        const float* w3i = w3 + iter * 32;
        #pragma unroll
        for (int k = 0; k < 32; k += 4) {
            float4 av0 = *(const float4*)&As[cur][ti][k];
            float4 av1 = *(const float4*)&As[cur][ti + 16][k];
            float4 bv0 = *(const float4*)&Bs[cur][tj][k];
            float4 bv1 = *(const float4*)&Bs[cur][tj + 16][k];
            const float4 wv = *(const float4*)(w3i + k);  // uniform -> s_load
            #define ACC(r, s, AV, BV) \
                c[r][s] = fmaf(AV.x, BV.x, c[r][s]); \
                c[r][s] = fmaf(AV.y, BV.y, c[r][s]); \
                c[r][s] = fmaf(AV.z, BV.z, c[r][s]); \
                c[r][s] = fmaf(AV.w, BV.w, c[r][s]); \
                t[r][s] = fmaf(fabsf(AV.x - BV.x), wv.x, t[r][s]); \
                t[r][s] = fmaf(fabsf(AV.y - BV.y), wv.y, t[r][s]); \
                t[r][s] = fmaf(fabsf(AV.z - BV.z), wv.z, t[r][s]); \
                t[r][s] = fmaf(fabsf(AV.w - BV.w), wv.w, t[r][s]);
            ACC(0, 0, av0, bv0)
            ACC(0, 1, av0, bv1)
            ACC(1, 0, av1, bv0)
            ACC(1, 1, av1, bv1)
            #undef ACC
        }
        if (more) {
            // consume prefetched regs: accumulate norms, then stage next buffer
            ssa += dot4(a0, a0);  t1a += dot4(a0, w1c);
            ssb += dot4(b0, b0);  t2b += dot4(b0, w2c);
            *(float4*)&As[cur ^ 1][lr][lc] = a0;
            *(float4*)&Bs[cur ^ 1][lr][lc] = b0;
            __syncthreads();
        }
    }

    // reduce norm/t1/t2 over the 8-thread lc-group (consecutive lanes)
    #pragma unroll
    for (int off = 1; off < 8; off <<= 1) {
        ssa += __shfl_xor(ssa, off);
        t1a += __shfl_xor(t1a, off);
        ssb += __shfl_xor(ssb, off);
        t2b += __shfl_xor(t2b, off);
    }
    if ((tid & 7) == 0) {
        smInvA[lr] = 1.f / fmaxf(sqrtf(ssa), COS_EPS);
        smT1A[lr]  = t1a;
        smInvB[lr] = 1.f / fmaxf(sqrtf(ssb), COS_EPS);
        smT2B[lr]  = t2b;
    }
    __syncthreads();

    // ---- epilogue ----
    const float bias = lb[0];
    float inv_n[2], t1_n[2], inv_m[2], t2_m[2];
    #pragma unroll
    for (int r = 0; r < 2; ++r) {
        inv_n[r] = smInvA[ti + 16 * r];
        t1_n[r]  = smT1A[ti + 16 * r];
    }
    #pragma unroll
    for (int s = 0; s < 2; ++s) {
        inv_m[s] = smInvB[tj + 16 * s];
        t2_m[s]  = smT2B[tj + 16 * s];
    }

    float bce = 0.f;
    float rowsum[2] = {0.f, 0.f};
    #pragma unroll
    for (int r = 0; r < 2; ++r) {
        #pragma unroll
        for (int s = 0; s < 2; ++s) {
            float cc = c[r][s] * inv_n[r] * inv_m[s];
            float lg = t1_n[r] + t2_m[s] + t[r][s] + bias;
            bce += softplus_f(isneg ? lg : -lg);
            if (isneg) {
                rowsum[r] += __expf(cc);
            } else {
                int n = n0 + ti + 16 * r;
                int m = m0 + tj + 16 * s;   // < NPOS here
                ws[OFF_COS + (size_t)n * NPOS + m] = cc;
            }
        }
    }

    if (isneg) {
        // reduce over the 16-lane tj group -> 32-col row sums; plain stores
        #pragma unroll
        for (int off = 1; off < 16; off <<= 1) {
            rowsum[0] += __shfl_xor(rowsum[0], off);
            rowsum[1] += __shfl_xor(rowsum[1], off);
        }
        const int mb = blockIdx.x - 16;   // 0..15 neg m-tile
        if (tj == 0) {
            ws[OFF_DENOP + mb * NPOS + n0 + ti]      = rowsum[0];
            ws[OFF_DENOP + mb * NPOS + n0 + ti + 16] = rowsum[1];
        }
    }

    // block-reduce BCE -> plain per-block partial (no atomic, no init needed)
    #pragma unroll
    for (int off = 32; off; off >>= 1) bce += __shfl_xor(bce, off);
    const int lane = tid & 63, wid = tid >> 6;
    if (lane == 0) red[wid] = bce;
    __syncthreads();
    if (tid == 0)
        ws[OFF_BCEP + bid] = red[0] + red[1] + red[2] + red[3];
}

// ---------------- Kernel 2: combine deno partials + closs + bce sum -------
// 256 blocks x 256 threads; block b handles pos rows {2b, 2b+1}:
// 128 threads per row, one float4 of cos each.
__global__ __launch_bounds__(256) void finish_kernel(
    float* __restrict__ ws, float* __restrict__ out)
{
    const int tid = threadIdx.x;
    const int n = blockIdx.x * 2 + (tid >> 7);
    const int tcol = tid & 127;
    const int lane = tid & 63;

    // deno_n = sum of 16 m-tile partials; every lane loads one of 16, xor-reduce
    float dn = ws[OFF_DENOP + (lane & 15) * NPOS + n];
    #pragma unroll
    for (int off = 1; off < 16; off <<= 1) dn += __shfl_xor(dn, off);

    float4 cc = *(const float4*)(ws + OFF_COS + (size_t)n * NPOS + 4 * tcol);
    float part = __logf(dn + __expf(cc.x) + EPSV) - cc.x
               + __logf(dn + __expf(cc.y) + EPSV) - cc.y
               + __logf(dn + __expf(cc.z) + EPSV) - cc.z
               + __logf(dn + __expf(cc.w) + EPSV) - cc.w;

    // fold in this block's two bce partials exactly once
    if (tid == 0)
        part += (ws[OFF_BCEP + 2 * blockIdx.x] + ws[OFF_BCEP + 2 * blockIdx.x + 1])
                * (1.f / 1024.f);

    #pragma unroll
    for (int off = 32; off; off >>= 1) part += __shfl_xor(part, off);
    if (lane == 0) atomicAdd(out, part);
}

extern "C" void kernel_launch(void* const* d_in, const int* in_sizes, int n_in,
                              void* d_out, int out_size, void* d_ws, size_t ws_size,
                              hipStream_t stream) {
    (void)in_sizes; (void)n_in; (void)out_size; (void)ws_size;
    const float* pos = (const float*)d_in[0];
    const float* neg = (const float*)d_in[1];
    const float* w   = (const float*)d_in[2];
    const float* lb  = (const float*)d_in[3];
    float* out = (float*)d_out;
    float* ws  = (float*)d_ws;

    mega_kernel<<<dim3(32, 16), 256, 0, stream>>>(pos, neg, w, lb, ws, out);
    finish_kernel<<<256, 256, 0, stream>>>(ws, out);
}

// Round 5
// 106.631 us; speedup vs baseline: 1.0638x; 1.0638x over previous
//
#include <hip/hip_runtime.h>
#include <math.h>

#define NPOS 512
#define DIM  512
#define NB   1024
#define EPSV 1e-5f
#define COS_EPS 1e-8f

// ws float offsets (~1.08 MB total -> L2-resident)
#define OFF_COS   0                           // [512*512] cos(pos_n, pos_m)
#define OFF_DENOP (NPOS * NPOS)               // [32*512]  deno partials (neg m-tile, n)
#define OFF_BCEP  (OFF_DENOP + 32 * NPOS)     // [1024]    per-block bce partials
#define OFF_INV   (OFF_BCEP + 1024)           // [1024]    inv norms, allv order
#define OFF_T1    (OFF_INV + NB)              // [512]     pos . w1
#define OFF_T2    (OFF_T1 + NPOS)             // [1024]    allv . w2

__device__ __forceinline__ float softplus_f(float x) {
    return fmaxf(x, 0.f) + __logf(1.f + __expf(-fabsf(x)));
}

// ---------------- Kernel 1: norms + t1 + t2 + out zero ----------------
__global__ __launch_bounds__(256) void prep_kernel(
    const float* __restrict__ pos, const float* __restrict__ neg,
    const float* __restrict__ w, float* __restrict__ ws, float* __restrict__ out)
{
    int gtid = blockIdx.x * 256 + threadIdx.x;
    if (gtid == 0) out[0] = 0.f;
    int row  = gtid >> 6;     // one wave per row, 1024 rows (allv order)
    int lane = threadIdx.x & 63;
    if (row >= NB) return;
    bool is_pos = row < NPOS;
    const float* r = is_pos ? pos + row * DIM : neg + (row - NPOS) * DIM;

    const float4* r4  = (const float4*)r + lane * 2;
    const float4* w14 = (const float4*)(w) + lane * 2;
    const float4* w24 = (const float4*)(w + DIM) + lane * 2;
    float4 a0 = r4[0],  a1 = r4[1];
    float4 u0 = w14[0], u1 = w14[1];
    float4 v0 = w24[0], v1 = w24[1];

    float ss  = a0.x*a0.x + a0.y*a0.y + a0.z*a0.z + a0.w*a0.w
              + a1.x*a1.x + a1.y*a1.y + a1.z*a1.z + a1.w*a1.w;
    float dw1 = a0.x*u0.x + a0.y*u0.y + a0.z*u0.z + a0.w*u0.w
              + a1.x*u1.x + a1.y*u1.y + a1.z*u1.z + a1.w*u1.w;
    float dw2 = a0.x*v0.x + a0.y*v0.y + a0.z*v0.z + a0.w*v0.w
              + a1.x*v1.x + a1.y*v1.y + a1.z*v1.z + a1.w*v1.w;

    #pragma unroll
    for (int off = 32; off; off >>= 1) {
        ss  += __shfl_xor(ss, off);
        dw1 += __shfl_xor(dw1, off);
        dw2 += __shfl_xor(dw2, off);
    }
    if (lane == 0) {
        float inv = 1.f / fmaxf(sqrtf(ss), COS_EPS);
        ws[OFF_INV + row] = inv;
        ws[OFF_T2 + row]  = dw2;
        if (is_pos) ws[OFF_T1 + row] = dw1;
    }
}

// ---------------- Kernel 2: fused cos + t3, full-k ----------------
// tile 32n x 16m, 2x2 microtile, 128 threads (2 waves), grid (64,16) =
// 1024 blocks = 4 blocks/CU: 4 independent barrier domains hide each
// other's staging stalls. Double-buffered LDS; read/write bank patterns
// are exactly conflict-free (As stride 36, Bs stride 20).
__global__ __launch_bounds__(128) void fused_kernel(
    const float* __restrict__ pos, const float* __restrict__ neg,
    const float* __restrict__ w, const float* __restrict__ lb,
    float* __restrict__ ws)
{
    __shared__ __align__(16) float As[2][32][36];
    __shared__ __align__(16) float Bs[2][16][20];
    __shared__ float red[2];

    const int tid = threadIdx.x;
    const int n0 = blockIdx.y * 32;
    const int m0 = blockIdx.x * 16;
    const int bid = blockIdx.y * 64 + blockIdx.x;
    const bool isneg = (m0 >= NPOS);
    const float* Asrc = pos + (size_t)n0 * DIM;
    const float* Bsrc = isneg ? (neg + (size_t)(m0 - NPOS) * DIM)
                              : (pos + (size_t)m0 * DIM);
    const float* w3 = w + 2 * DIM;

    // staging indices: A 32x32/iter (2 float4/thread), B 16x32 (1 float4/thread)
    const int lrA = tid >> 2;            // 0..31
    const int lcA = (tid & 3) << 3;      // 0,8,16,24
    const int lrB = tid >> 3;            // 0..15
    const int lcB = (tid & 7) << 2;      // 0..28
    // compute indices: rows {ti, ti+16}, cols {tj, tj+8}
    const int ti = tid >> 3;             // 0..15
    const int tj = tid & 7;              // 0..7

    float c[2][2] = {{0.f}}, t[2][2] = {{0.f}};

    // prologue staging (chunk 0)
    float4 a0 = *(const float4*)(Asrc + lrA * DIM + lcA);
    float4 a1 = *(const float4*)(Asrc + lrA * DIM + lcA + 4);
    float4 b0 = *(const float4*)(Bsrc + lrB * DIM + lcB);
    *(float4*)&As[0][lrA][lcA]     = a0;
    *(float4*)&As[0][lrA][lcA + 4] = a1;
    *(float4*)&Bs[0][lrB][lcB]     = b0;
    __syncthreads();

    #pragma unroll 1
    for (int iter = 0; iter < DIM / 32; ++iter) {
        const int cur = iter & 1;
        const bool more = (iter < DIM / 32 - 1);
        if (more) {   // issue next-chunk loads early (L2 latency hidden by FMAs)
            const float* ap = Asrc + (iter + 1) * 32;
            const float* bp = Bsrc + (iter + 1) * 32;
            a0 = *(const float4*)(ap + lrA * DIM + lcA);
            a1 = *(const float4*)(ap + lrA * DIM + lcA + 4);
            b0 = *(const float4*)(bp + lrB * DIM + lcB);
        }
        const float* w3i = w3 + iter * 32;
        #pragma unroll
        for (int k = 0; k < 32; k += 4) {
            float4 av0 = *(const float4*)&As[cur][ti][k];
            float4 av1 = *(const float4*)&As[cur][ti + 16][k];
            float4 bv0 = *(const float4*)&Bs[cur][tj][k];
            float4 bv1 = *(const float4*)&Bs[cur][tj + 8][k];
            const float4 wv = *(const float4*)(w3i + k);  // uniform -> s_load
            #define ACC(r, s, AV, BV) \
                c[r][s] = fmaf(AV.x, BV.x, c[r][s]); \
                c[r][s] = fmaf(AV.y, BV.y, c[r][s]); \
                c[r][s] = fmaf(AV.z, BV.z, c[r][s]); \
                c[r][s] = fmaf(AV.w, BV.w, c[r][s]); \
                t[r][s] = fmaf(fabsf(AV.x - BV.x), wv.x, t[r][s]); \
                t[r][s] = fmaf(fabsf(AV.y - BV.y), wv.y, t[r][s]); \
                t[r][s] = fmaf(fabsf(AV.z - BV.z), wv.z, t[r][s]); \
                t[r][s] = fmaf(fabsf(AV.w - BV.w), wv.w, t[r][s]);
            ACC(0, 0, av0, bv0)
            ACC(0, 1, av0, bv1)
            ACC(1, 0, av1, bv0)
            ACC(1, 1, av1, bv1)
            #undef ACC
        }
        if (more) {
            *(float4*)&As[cur ^ 1][lrA][lcA]     = a0;
            *(float4*)&As[cur ^ 1][lrA][lcA + 4] = a1;
            *(float4*)&Bs[cur ^ 1][lrB][lcB]     = b0;
            __syncthreads();
        }
    }

    // ---- epilogue ----
    const float bias = lb[0];
    float inv_n[2], t1_n[2], inv_m[2], t2_m[2];
    #pragma unroll
    for (int r = 0; r < 2; ++r) {
        int n = n0 + ti + 16 * r;
        inv_n[r] = ws[OFF_INV + n];
        t1_n[r]  = ws[OFF_T1 + n];
    }
    #pragma unroll
    for (int s = 0; s < 2; ++s) {
        int m = m0 + tj + 8 * s;       // allv index
        inv_m[s] = ws[OFF_INV + m];
        t2_m[s]  = ws[OFF_T2 + m];
    }

    float bce = 0.f;
    float rowsum[2] = {0.f, 0.f};
    #pragma unroll
    for (int r = 0; r < 2; ++r) {
        #pragma unroll
        for (int s = 0; s < 2; ++s) {
            float cc = c[r][s] * inv_n[r] * inv_m[s];
            float lg = t1_n[r] + t2_m[s] + t[r][s] + bias;
            bce += softplus_f(isneg ? lg : -lg);
            if (isneg) {
                rowsum[r] += __expf(cc);
            } else {
                int n = n0 + ti + 16 * r;
                int m = m0 + tj + 8 * s;    // < NPOS here
                ws[OFF_COS + (size_t)n * NPOS + m] = cc;
            }
        }
    }

    if (isneg) {
        // reduce over the 8-lane tj group -> 16-col row sums; plain stores
        #pragma unroll
        for (int off = 1; off < 8; off <<= 1) {
            rowsum[0] += __shfl_xor(rowsum[0], off);
            rowsum[1] += __shfl_xor(rowsum[1], off);
        }
        const int mb = blockIdx.x - 32;   // 0..31 neg m-tile
        if (tj == 0) {
            ws[OFF_DENOP + mb * NPOS + n0 + ti]      = rowsum[0];
            ws[OFF_DENOP + mb * NPOS + n0 + ti + 16] = rowsum[1];
        }
    }

    // block-reduce BCE -> plain per-block partial
    #pragma unroll
    for (int off = 32; off; off >>= 1) bce += __shfl_xor(bce, off);
    const int lane = tid & 63, wid = tid >> 6;
    if (lane == 0) red[wid] = bce;
    __syncthreads();
    if (tid == 0) ws[OFF_BCEP + bid] = red[0] + red[1];
}

// ---------------- Kernel 3: deno combine + closs + bce fold ----------------
// 256 blocks x 256 threads; block b handles pos rows {2b, 2b+1} and bce
// partials {4b..4b+3}. 128 threads per row, one float4 of cos each.
__global__ __launch_bounds__(256) void finish_kernel(
    float* __restrict__ ws, float* __restrict__ out)
{
    const int tid = threadIdx.x;
    const int n = blockIdx.x * 2 + (tid >> 7);
    const int tcol = tid & 127;
    const int lane = tid & 63;

    // deno_n = sum of 32 m-tile partials: lanes 0..31 / 32..63 each load one
    float dn = ws[OFF_DENOP + (lane & 31) * NPOS + n];
    #pragma unroll
    for (int off = 1; off < 32; off <<= 1) dn += __shfl_xor(dn, off);

    float4 cc = *(const float4*)(ws + OFF_COS + (size_t)n * NPOS + 4 * tcol);
    float part = __logf(dn + __expf(cc.x) + EPSV) - cc.x
               + __logf(dn + __expf(cc.y) + EPSV) - cc.y
               + __logf(dn + __expf(cc.z) + EPSV) - cc.z
               + __logf(dn + __expf(cc.w) + EPSV) - cc.w;

    if (tid == 0) {
        const float* bp = ws + OFF_BCEP + 4 * blockIdx.x;
        part += (bp[0] + bp[1] + bp[2] + bp[3]) * (1.f / 1024.f);
    }

    #pragma unroll
    for (int off = 32; off; off >>= 1) part += __shfl_xor(part, off);
    if (lane == 0) atomicAdd(out, part);
}

extern "C" void kernel_launch(void* const* d_in, const int* in_sizes, int n_in,
                              void* d_out, int out_size, void* d_ws, size_t ws_size,
                              hipStream_t stream) {
    (void)in_sizes; (void)n_in; (void)out_size; (void)ws_size;
    const float* pos = (const float*)d_in[0];
    const float* neg = (const float*)d_in[1];
    const float* w   = (const float*)d_in[2];
    const float* lb  = (const float*)d_in[3];
    float* out = (float*)d_out;
    float* ws  = (float*)d_ws;

    prep_kernel<<<256, 256, 0, stream>>>(pos, neg, w, ws, out);
    fused_kernel<<<dim3(64, 16), 128, 0, stream>>>(pos, neg, w, lb, ws);
    finish_kernel<<<256, 256, 0, stream>>>(ws, out);
}